// Round 7
// baseline (267.441 us; speedup 1.0000x reference)
//
#include <hip/hip_runtime.h>
#include <stdint.h>

#define BATCH    256
#define VOCAB    128000
#define HIST     200
#define TOPK     50
#define BITWORDS (VOCAB / 32)   // 4000 words = 16000 B

// --- fused-path parameters ---
#define SLICES   8              // collect blocks per row
#define CBLK     (BATCH * SLICES)   // 2048 collect blocks
#define ZBLK     2000           // zero blocks: 2000 x 4096 float4 = 8,192,000 exactly
#define ZCHUNK   4096           // contiguous float4 per zero block (64 KB)
#define NT1      256            // threads, fused kernel
#define NT2      512            // threads, select kernel
#define LCAP     1024           // candidate capacity per row (expected ~173)
#define TRAW     3.0f           // pre-penalty threshold; P(N(0,1)>3)*128000 ~= 173

// --- monolithic fallback (original kernel) parameters ---
#define CAP      2048
#define NTHREADS 1024

typedef float f32x4_t __attribute__((ext_vector_type(4)));

// Monotonic float->uint key: descending float order == descending unsigned order.
__device__ __forceinline__ unsigned fkey_of(float f) {
  unsigned u = __float_as_uint(f);
  return (u & 0x80000000u) ? ~u : (u | 0x80000000u);
}
__device__ __forceinline__ float f_of_key(unsigned k) {
  unsigned u = (k & 0x80000000u) ? (k & 0x7FFFFFFFu) : ~k;
  return __uint_as_float(u);
}

__device__ __forceinline__ void push4(float4 v, unsigned v0,
                                      int* __restrict__ cnt,
                                      uint2* __restrict__ cand) {
  if (v.x > TRAW) { int p = atomicAdd(cnt, 1); if (p < LCAP) cand[p] = make_uint2(__float_as_uint(v.x), v0 + 0u); }
  if (v.y > TRAW) { int p = atomicAdd(cnt, 1); if (p < LCAP) cand[p] = make_uint2(__float_as_uint(v.y), v0 + 1u); }
  if (v.z > TRAW) { int p = atomicAdd(cnt, 1); if (p < LCAP) cand[p] = make_uint2(__float_as_uint(v.z), v0 + 2u); }
  if (v.w > TRAW) { int p = atomicAdd(cnt, 1); if (p < LCAP) cand[p] = make_uint2(__float_as_uint(v.w), v0 + 3u); }
}

__device__ __forceinline__ float max4(float4 v) {
  return fmaxf(fmaxf(v.x, v.y), fmaxf(v.z, v.w));
}

// ============================================================================
// Fused kernel: block-specialized zero + collect.
//  - blocks [0, ZBLK):     each zeroes ONE contiguous 64 KB region of out
//                          with plain cached float4 stores (harness's rocclr
//                          fill proves this allocation sustains 6.4 TB/s of
//                          dense stores from a 256-thread kernel).
//  - blocks [ZBLK,+CBLK):  READ-ONLY collect with FORCED 4-deep MLP: all 4
//                          float4 loads are consumed by a single fmax tree
//                          BEFORE any branch, so all 16 values are live at
//                          once -> compiler must keep 4 loads in flight
//                          (check: VGPR_Count must rise from 16 to >=28).
//                          Every prior collect had VGPR=16 == one load in
//                          flight == the ~1.8 TB/s cap seen in all rounds.
// ============================================================================
__global__ __launch_bounds__(NT1) void fused_zc_kernel(
    const float* __restrict__ logits, float* __restrict__ out,
    int* __restrict__ cnt_g, uint2* __restrict__ cand_g)
{
  const int bid = blockIdx.x;

  if (bid < ZBLK) {
    // ---- zeroing blocks: contiguous 64 KB per block, cached stores ----
    const f32x4_t z4 = (f32x4_t)0.f;
    f32x4_t* o4 = (f32x4_t*)out + (size_t)bid * ZCHUNK;
    #pragma unroll
    for (int k = 0; k < ZCHUNK / NT1; ++k)     // 16 contiguous wave-steps
      o4[k * NT1 + threadIdx.x] = z4;
    return;
  }

  // ---- collect blocks: read-only, forced-MLP batch of 4 ----
  const int cid = bid - ZBLK;
  const int b = cid >> 3;            // SLICES == 8
  const int s = cid & (SLICES - 1);
  const float4* row4 = (const float4*)(logits + (size_t)b * VOCAB);
  const int per = (VOCAB / 4) / SLICES;   // 4000 float4 per slice
  const int lo = s * per, hi = lo + per;
  int*   cnt  = cnt_g + b;
  uint2* cand = cand_g + (size_t)b * LCAP;

  int i = lo + (int)threadIdx.x;

  for (; i + 3 * NT1 < hi; i += 4 * NT1) {
    float4 a  = row4[i];
    float4 b4 = row4[i + NT1];
    float4 c  = row4[i + 2 * NT1];
    float4 d  = row4[i + 3 * NT1];
    // Single reduction over all 16 values BEFORE any branch: forces a,b4,c,d
    // simultaneously live -> 4 loads issued back-to-back, staged vmcnt.
    float m = fmaxf(fmaxf(max4(a), max4(b4)), fmaxf(max4(c), max4(d)));
    if (m > TRAW) {                       // taken by ~2% of lane-batches
      push4(a,  4u * (unsigned)i,             cnt, cand);
      push4(b4, 4u * (unsigned)(i + NT1),     cnt, cand);
      push4(c,  4u * (unsigned)(i + 2 * NT1), cnt, cand);
      push4(d,  4u * (unsigned)(i + 3 * NT1), cnt, cand);
    }
  }
  // tail
  for (; i < hi; i += NT1) {
    float4 a = row4[i];
    if (max4(a) > TRAW) push4(a, 4u * (unsigned)i, cnt, cand);
  }
}

// ============================================================================
// Select kernel: per-row selection. 256 blocks x 512 threads. Penalty +
// temperature on ~173 candidates, rank sort (keys unique via idx tie-break ->
// bijection), top-k boundary w/ ties, nucleus cutoff, scatter.
// Self-contained bisection rescan fallback if the candidate set is invalid
// (never for this input distribution).
// ============================================================================
__global__ __launch_bounds__(NT2) void select_kernel(
    const float* __restrict__ logits, const int* __restrict__ prev,
    float* __restrict__ out, const int* __restrict__ cnt_g,
    const uint2* __restrict__ cand_g)
{
  __shared__ unsigned bitmask[BITWORDS];          // 16000 B
  __shared__ unsigned long long keys[LCAP];       //  8192 B
  __shared__ unsigned long long skeys[LCAP];      //  8192 B
  __shared__ float evals[LCAP];                   //  4096 B
  __shared__ int s_cnt, s_good, s_m, s_j;
  __shared__ float s_maxx, s_Z2;

  const int b   = blockIdx.x;
  const int tid = threadIdx.x;
  const float* row  = logits + (size_t)b * VOCAB;
  float*       orow = out    + (size_t)b * VOCAB;

  // ---- seen-token bitmask ----
  for (int i = tid; i < BITWORDS; i += NT2) bitmask[i] = 0u;
  if (tid == 0) s_good = 0;
  __syncthreads();
  for (int i = tid; i < HIST; i += NT2) {
    int t = prev[b * HIST + i];
    atomicOr(&bitmask[t >> 5], 1u << (t & 31));
  }
  __syncthreads();

  // ---- fast path: penalize + temperature the collected candidates ----
  int cnt = cnt_g[b];
  int mn = cnt < LCAP ? cnt : LCAP;
  const uint2* cand = cand_g + (size_t)b * LCAP;
  for (int i = tid; i < mn; i += NT2) {
    uint2 c = cand[i];
    float v = __uint_as_float(c.x);
    unsigned idx = c.y;
    float y = v;
    if ((bitmask[idx >> 5] >> (idx & 31)) & 1u)
      y = (v < 0.0f) ? v * 1.2f : v / 1.2f;        // repetition penalty
    float x = y / 0.6f;                            // temperature (exact IEEE div)
    keys[i] = ((unsigned long long)fkey_of(x) << 32) |
              (unsigned)(~idx);                    // tie-break: smaller idx first
    if (y > TRAW) atomicAdd(&s_good, 1);
  }
  __syncthreads();

  // Valid iff all tokens with y > TRAW were collected AND >= TOPK of them exist
  // (tokens not collected have y <= TRAW, so kth_y > TRAW guarantees coverage).
  if (cnt > LCAP || s_good < TOPK) {
    // ---- fallback: bisection rescan from global memory (rare/never) ----
    float T = TRAW;
    float Tlo = 0.f, Thi = 0.f;
    bool hasLo = false, hasHi = false;
    const float4* row4 = (const float4*)row;
    const int N4 = VOCAB / 4;
    for (int attempt = 0; attempt < 40; ++attempt) {
      __syncthreads();
      if (tid == 0) s_cnt = 0;
      __syncthreads();
      for (int i = tid; i < N4; i += NT2) {
        float4 v4 = row4[i];
        int v0 = i * 4;
        unsigned w  = bitmask[v0 >> 5];
        unsigned sh = v0 & 31;
        float vv[4] = {v4.x, v4.y, v4.z, v4.w};
        #pragma unroll
        for (int l = 0; l < 4; ++l) {
          float v = vv[l];
          float y = v;
          if ((w >> (sh + l)) & 1u)
            y = (v < 0.0f) ? v * 1.2f : v / 1.2f;
          if (y > T) {
            int pos = atomicAdd(&s_cnt, 1);
            if (pos < LCAP) {
              unsigned k = fkey_of(y / 0.6f);
              keys[pos] = ((unsigned long long)k << 32) |
                          (unsigned)(~(unsigned)(v0 + l));
            }
          }
        }
      }
      __syncthreads();
      cnt = s_cnt;
      if (cnt >= TOPK && cnt <= LCAP) break;
      if (cnt < TOPK) { Thi = T; hasHi = true; T = hasLo ? 0.5f * (T + Tlo) : T - 1.0f; }
      else            { Tlo = T; hasLo = true; T = hasHi ? 0.5f * (T + Thi) : T + 1.0f; }
    }
    if (cnt > LCAP) cnt = LCAP;
  }

  // ---- rank sort: keys unique (idx tie-break) => ranks are a bijection ----
  // cnt ~173: each thread ranks <=1 key with an LDS-broadcast inner loop.
  for (int i = tid; i < cnt; i += NT2) {
    unsigned long long a = keys[i];
    int r = 0;
    for (int j = 0; j < cnt; ++j) r += (keys[j] > a);
    skeys[r] = a;
  }
  __syncthreads();

  // ---- top-k boundary (keep ties at kth) + max ----
  if (tid == 0) {
    int kk = (cnt < TOPK) ? cnt : TOPK;
    unsigned kth = (unsigned)(skeys[kk - 1] >> 32);
    int m = kk;
    while (m < cnt && (unsigned)(skeys[m] >> 32) == kth) m++;
    s_m = m;
    s_maxx = f_of_key((unsigned)(skeys[0] >> 32));
  }
  __syncthreads();
  int m = s_m;
  float maxx = s_maxx;
  for (int i = tid; i < m; i += NT2)
    evals[i] = expf(f_of_key((unsigned)(skeys[i] >> 32)) - maxx);
  __syncthreads();

  // ---- nucleus cutoff: keep token i iff i==0 or cumsum(p[0..i-1]) <= 0.9 ----
  if (tid == 0) {
    float Z = 0.f;
    for (int i = 0; i < m; ++i) Z += evals[i];
    float cum = 0.f;
    int j = 0;
    for (int i = 0; i < m; ++i) {
      if (i > 0 && cum > 0.9f) break;
      cum += evals[i] / Z;
      j = i + 1;
    }
    float Z2 = 0.f;
    for (int i = 0; i < j; ++i) Z2 += evals[i];
    s_j = j; s_Z2 = Z2;
  }
  __syncthreads();

  // ---- scatter final probs (row already zeroed) ----
  int j = s_j;
  float Z2 = s_Z2;
  for (int i = tid; i < j; i += NT2) {
    int idx = (int)(~(unsigned)(skeys[i] & 0xFFFFFFFFull));
    orow[idx] = evals[i] / Z2;
  }
}

// ============================================================================
// Monolithic fallback (round-0 kernel) — used only if ws_size is too small
// for the multi-kernel workspace.
// ============================================================================
__global__ __launch_bounds__(NTHREADS) void sample_head_kernel(
    const float* __restrict__ logits, const int* __restrict__ prev,
    float* __restrict__ out)
{
  __shared__ unsigned bitmask[BITWORDS];
  __shared__ unsigned long long keys[CAP];
  __shared__ float evals[CAP];
  __shared__ int s_count;
  __shared__ int s_m, s_j;
  __shared__ float s_maxx, s_Z2;

  const int b   = blockIdx.x;
  const int tid = threadIdx.x;
  const float* row  = logits + (size_t)b * VOCAB;
  float*       orow = out    + (size_t)b * VOCAB;

  for (int i = tid; i < BITWORDS; i += NTHREADS) bitmask[i] = 0u;
  __syncthreads();
  for (int i = tid; i < HIST; i += NTHREADS) {
    int t = prev[b * HIST + i];
    atomicOr(&bitmask[t >> 5], 1u << (t & 31));
  }
  __syncthreads();

  float T = 3.0f;
  float Tlo = 0.f, Thi = 0.f;
  bool hasLo = false, hasHi = false;
  int cnt = 0;

  const float4* row4  = (const float4*)row;
  float4*       orow4 = (float4*)orow;
  const int N4 = VOCAB / 4;

  for (int attempt = 0; attempt < 40; ++attempt) {
    __syncthreads();
    if (tid == 0) s_count = 0;
    __syncthreads();

    for (int i = tid; i < N4; i += NTHREADS) {
      float4 v4 = row4[i];
      if (attempt == 0) orow4[i] = make_float4(0.f, 0.f, 0.f, 0.f);
      int v0 = i * 4;
      unsigned w  = bitmask[v0 >> 5];
      unsigned sh = v0 & 31;
      float vv[4] = {v4.x, v4.y, v4.z, v4.w};
      #pragma unroll
      for (int l = 0; l < 4; ++l) {
        float v = vv[l];
        float y = v;
        if ((w >> (sh + l)) & 1u)
          y = (v < 0.0f) ? v * 1.2f : v / 1.2f;
        if (y > T) {
          float x = y / 0.6f;
          int pos = atomicAdd(&s_count, 1);
          if (pos < CAP) {
            unsigned k = fkey_of(x);
            keys[pos] = ((unsigned long long)k << 32) |
                        (unsigned)(~(unsigned)(v0 + l));
          }
        }
      }
    }
    __syncthreads();
    cnt = s_count;
    if (cnt >= TOPK && cnt <= CAP) break;
    if (cnt < TOPK) { Thi = T; hasHi = true; T = hasLo ? 0.5f * (T + Tlo) : T - 1.0f; }
    else            { Tlo = T; hasLo = true; T = hasHi ? 0.5f * (T + Thi) : T + 1.0f; }
  }
  if (cnt > CAP) cnt = CAP;

  int n = 64;
  while (n < cnt) n <<= 1;
  for (int i = cnt + tid; i < n; i += NTHREADS) keys[i] = 0ull;
  __syncthreads();
  for (int k = 2; k <= n; k <<= 1) {
    for (int j = k >> 1; j > 0; j >>= 1) {
      for (int i = tid; i < n; i += NTHREADS) {
        int l = i ^ j;
        if (l > i) {
          unsigned long long a = keys[i], c = keys[l];
          bool up = (i & k) == 0;
          if (up ? (a < c) : (a > c)) { keys[i] = c; keys[l] = a; }
        }
      }
      __syncthreads();
    }
  }

  if (tid == 0) {
    int kk = (cnt < TOPK) ? cnt : TOPK;
    unsigned kth = (unsigned)(keys[kk - 1] >> 32);
    int m = kk;
    while (m < cnt && (unsigned)(keys[m] >> 32) == kth) m++;
    s_m = m;
    s_maxx = f_of_key((unsigned)(keys[0] >> 32));
  }
  __syncthreads();
  int m = s_m;
  float maxx = s_maxx;
  for (int i = tid; i < m; i += NTHREADS)
    evals[i] = expf(f_of_key((unsigned)(keys[i] >> 32)) - maxx);
  __syncthreads();

  if (tid == 0) {
    float Z = 0.f;
    for (int i = 0; i < m; ++i) Z += evals[i];
    float cum = 0.f;
    int j = 0;
    for (int i = 0; i < m; ++i) {
      if (i > 0 && cum > 0.9f) break;
      cum += evals[i] / Z;
      j = i + 1;
    }
    float Z2 = 0.f;
    for (int i = 0; i < j; ++i) Z2 += evals[i];
    s_j = j; s_Z2 = Z2;
  }
  __syncthreads();

  int j = s_j;
  float Z2 = s_Z2;
  for (int i = tid; i < j; i += NTHREADS) {
    int idx = (int)(~(unsigned)(keys[i] & 0xFFFFFFFFull));
    orow[idx] = evals[i] / Z2;
  }
}

extern "C" void kernel_launch(void* const* d_in, const int* in_sizes, int n_in,
                              void* d_out, int out_size, void* d_ws, size_t ws_size,
                              hipStream_t stream) {
  const float* logits = (const float*)d_in[0];
  const int*   prev   = (const int*)d_in[1];
  float*       out    = (float*)d_out;

  const size_t cnt_bytes  = (size_t)BATCH * sizeof(int);
  const size_t cand_off   = 1024;  // 8B-aligned, past counters
  const size_t need       = cand_off + (size_t)BATCH * LCAP * sizeof(uint2);

  if (d_ws != nullptr && ws_size >= need) {
    int*   cnt_g  = (int*)d_ws;
    uint2* cand_g = (uint2*)((char*)d_ws + cand_off);
    hipMemsetAsync(d_ws, 0, cnt_bytes, stream);
    hipLaunchKernelGGL(fused_zc_kernel, dim3(ZBLK + CBLK), dim3(NT1),
                       0, stream, logits, out, cnt_g, cand_g);
    hipLaunchKernelGGL(select_kernel, dim3(BATCH), dim3(NT2),
                       0, stream, logits, prev, out, cnt_g, cand_g);
  } else {
    hipLaunchKernelGGL(sample_head_kernel, dim3(BATCH), dim3(NTHREADS),
                       0, stream, logits, prev, out);
  }
}

// Round 8
// 241.938 us; speedup vs baseline: 1.1054x; 1.1054x over previous
//
#include <hip/hip_runtime.h>
#include <stdint.h>

#define BATCH    256
#define VOCAB    128000
#define HIST     200
#define TOPK     50
#define CAP      2048
#define NTHREADS 1024
#define BITWORDS (VOCAB / 32)   // 4000 words = 16000 B

// ----------------------------------------------------------------------------
// Structure rationale (rounds 0-7 evidence):
//  * d_out accepts writes at only ~1.6-1.7 TB/s regardless of writer
//    (rocclr fill: 6.5 TB/s on d_ws vs 1.66 TB/s on d_out; our NT/cached/
//    contiguous sweeps all ~1.5-1.7). 131 MB of zeros+scatter => ~80 us floor.
//  * logits reads run at 6+ TB/s (collect-only kernel ~14 us).
//  * Therefore: ONE kernel, one block per row, where the row's zero-stores
//    are issued up front and everything else (collect, sort, softmax) hides
//    under the write drain. Extra dispatches after the write phase only ADD
//    serial time (R4/R6 regressions).
//  * Bitonic sort's ~36 __syncthreads each force a vmcnt(0) drain of the
//    block's outstanding 500 KB write stream -> replaced by a 2-barrier
//    rank sort (keys unique via idx tie-break => ranks are a bijection).
// ----------------------------------------------------------------------------

// Monotonic float->uint key: descending float order == descending unsigned order.
__device__ __forceinline__ unsigned fkey_of(float f) {
  unsigned u = __float_as_uint(f);
  return (u & 0x80000000u) ? ~u : (u | 0x80000000u);
}
__device__ __forceinline__ float f_of_key(unsigned k) {
  unsigned u = (k & 0x80000000u) ? (k & 0x7FFFFFFFu) : ~k;
  return __uint_as_float(u);
}

__global__ __launch_bounds__(NTHREADS) void sample_head_kernel(
    const float* __restrict__ logits, const int* __restrict__ prev,
    float* __restrict__ out)
{
  __shared__ unsigned bitmask[BITWORDS];          // 16000 B
  __shared__ unsigned long long keys[CAP];        // 16384 B
  __shared__ unsigned long long skeys[CAP];       // 16384 B
  __shared__ float evals[CAP];                    //  8192 B
  __shared__ int s_count;
  __shared__ int s_m, s_j;
  __shared__ float s_maxx, s_Z2;

  const int b   = blockIdx.x;
  const int tid = threadIdx.x;
  const float* row  = logits + (size_t)b * VOCAB;
  float*       orow = out    + (size_t)b * VOCAB;

  // ---- seen-token bitmask ----
  for (int i = tid; i < BITWORDS; i += NTHREADS) bitmask[i] = 0u;
  if (tid == 0) s_count = 0;
  __syncthreads();
  for (int i = tid; i < HIST; i += NTHREADS) {
    int t = prev[b * HIST + i];
    atomicOr(&bitmask[t >> 5], 1u << (t & 31));
  }
  __syncthreads();

  const float4* row4  = (const float4*)row;
  float4*       orow4 = (float4*)orow;
  const int N4 = VOCAB / 4;       // 32000

  // T is in pre-temperature (y) space. y ~ N(0,1); kth@50/128000 ~= 3.36 sigma.
  float T = 3.0f;                 // expected count(y>T) ~= 173 in [TOPK, CAP]

  // ---- pass 0 (peeled): zero row + collect.  Zero-stores issued first so
  // the slow d_out write stream drains under all subsequent work. ----
  for (int i = tid; i < N4; i += NTHREADS) {
    float4 v4 = row4[i];
    orow4[i] = make_float4(0.f, 0.f, 0.f, 0.f);
    int v0 = i * 4;
    unsigned w  = bitmask[v0 >> 5];
    unsigned sh = v0 & 31;
    float vv[4] = {v4.x, v4.y, v4.z, v4.w};
    #pragma unroll
    for (int l = 0; l < 4; ++l) {
      float v = vv[l];
      float y = v;
      if ((w >> (sh + l)) & 1u)                       // repetition penalty (rare)
        y = (v < 0.0f) ? v * 1.2f : v / 1.2f;
      if (y > T) {                                    // superset of top-k set
        float x = y / 0.6f;                           // temperature (exact IEEE div)
        int pos = atomicAdd(&s_count, 1);
        if (pos < CAP) {
          unsigned k = fkey_of(x);
          keys[pos] = ((unsigned long long)k << 32) |
                      (unsigned)(~(unsigned)(v0 + l)); // tie-break: smaller idx first
        }
      }
    }
  }
  __syncthreads();
  int cnt = s_count;

  // ---- retry passes (bisection safety net; never taken for this input) ----
  if (cnt < TOPK || cnt > CAP) {
    float Tlo = 0.f, Thi = 0.f;
    bool hasLo = false, hasHi = false;
    for (int attempt = 0; attempt < 40; ++attempt) {
      if (cnt < TOPK) { Thi = T; hasHi = true; T = hasLo ? 0.5f * (T + Tlo) : T - 1.0f; }
      else            { Tlo = T; hasLo = true; T = hasHi ? 0.5f * (T + Thi) : T + 1.0f; }
      __syncthreads();
      if (tid == 0) s_count = 0;
      __syncthreads();
      for (int i = tid; i < N4; i += NTHREADS) {
        float4 v4 = row4[i];
        int v0 = i * 4;
        unsigned w  = bitmask[v0 >> 5];
        unsigned sh = v0 & 31;
        float vv[4] = {v4.x, v4.y, v4.z, v4.w};
        #pragma unroll
        for (int l = 0; l < 4; ++l) {
          float v = vv[l];
          float y = v;
          if ((w >> (sh + l)) & 1u)
            y = (v < 0.0f) ? v * 1.2f : v / 1.2f;
          if (y > T) {
            float x = y / 0.6f;
            int pos = atomicAdd(&s_count, 1);
            if (pos < CAP) {
              unsigned k = fkey_of(x);
              keys[pos] = ((unsigned long long)k << 32) |
                          (unsigned)(~(unsigned)(v0 + l));
            }
          }
        }
      }
      __syncthreads();
      cnt = s_count;
      if (cnt >= TOPK && cnt <= CAP) break;
    }
    if (cnt > CAP) cnt = CAP;   // pathological-tie fallback (never for this input)
  }

  // ---- rank sort: keys unique (idx tie-break) => ranks are a bijection.
  // 2 barriers total vs bitonic's ~36 (each barrier drains the write queue).
  for (int i = tid; i < cnt; i += NTHREADS) {
    unsigned long long a = keys[i];
    int r = 0;
    for (int j = 0; j < cnt; ++j) r += (keys[j] > a);
    skeys[r] = a;
  }
  __syncthreads();

  // ---- top-k boundary (keep ties at kth) + max ----
  if (tid == 0) {
    int kk = (cnt < TOPK) ? cnt : TOPK;
    unsigned kth = (unsigned)(skeys[kk - 1] >> 32);
    int m = kk;
    while (m < cnt && (unsigned)(skeys[m] >> 32) == kth) m++;
    s_m = m;
    s_maxx = f_of_key((unsigned)(skeys[0] >> 32));
  }
  __syncthreads();
  int m = s_m;
  float maxx = s_maxx;
  for (int i = tid; i < m; i += NTHREADS)
    evals[i] = expf(f_of_key((unsigned)(skeys[i] >> 32)) - maxx);
  __syncthreads();

  // ---- nucleus cutoff: keep token i iff i==0 or cumsum(p[0..i-1]) <= 0.9 ----
  if (tid == 0) {
    float Z = 0.f;
    for (int i = 0; i < m; ++i) Z += evals[i];
    float cum = 0.f;
    int j = 0;
    for (int i = 0; i < m; ++i) {
      if (i > 0 && cum > 0.9f) break;
      cum += evals[i] / Z;
      j = i + 1;
    }
    float Z2 = 0.f;
    for (int i = 0; i < j; ++i) Z2 += evals[i];
    s_j = j; s_Z2 = Z2;
  }
  __syncthreads();

  // ---- scatter final probs (row zeroed in pass 0; barrier above drained
  // the write queue, so ordering vs the zeros is guaranteed) ----
  int j = s_j;
  float Z2 = s_Z2;
  for (int i = tid; i < j; i += NTHREADS) {
    int idx = (int)(~(unsigned)(skeys[i] & 0xFFFFFFFFull));
    orow[idx] = evals[i] / Z2;
  }
}

extern "C" void kernel_launch(void* const* d_in, const int* in_sizes, int n_in,
                              void* d_out, int out_size, void* d_ws, size_t ws_size,
                              hipStream_t stream) {
  const float* logits = (const float*)d_in[0];
  const int*   prev   = (const int*)d_in[1];
  float*       out    = (float*)d_out;
  hipLaunchKernelGGL(sample_head_kernel, dim3(BATCH), dim3(NTHREADS), 0, stream,
                     logits, prev, out);
}